// Round 10
// baseline (560.388 us; speedup 1.0000x reference)
//
#include <hip/hip_runtime.h>
#include <math.h>

#define B_ 32
#define S_ 4096
#define CTXD_ 512
#define QD_ 512
#define ATTD_ 256

#define RT 64          // rows (s) per block
#define NCH (S_ / RT)  // 64 chunks per batch row

#define MASKED_SCORE (-1e30f)

typedef __attribute__((ext_vector_type(8))) short bf16x8;   // 8 bf16 = 4 VGPR
typedef __attribute__((ext_vector_type(4))) float f32x4;    // MFMA C/D

// fp32 -> bf16 round-to-nearest-even (inputs are finite randoms)
__device__ __forceinline__ unsigned short f2bf(float f) {
    unsigned u = __float_as_uint(f);
    u += 0x7fff + ((u >> 16) & 1);
    return (unsigned short)(u >> 16);
}
__device__ __forceinline__ unsigned pk2(float lo, float hi) {
    return (unsigned)f2bf(lo) | ((unsigned)f2bf(hi) << 16);
}
__device__ __forceinline__ bf16x8 cvt8(float4 lo, float4 hi) {
    union { unsigned u[4]; bf16x8 v; } r;
    r.u[0] = pk2(lo.x, lo.y);
    r.u[1] = pk2(lo.z, lo.w);
    r.u[2] = pk2(hi.x, hi.y);
    r.u[3] = pk2(hi.z, hi.w);
    return r.v;
}
__device__ __forceinline__ bf16x8 ld_bf8(const unsigned short* p) {
    union { uint4 q; bf16x8 v; } r;
    r.q = *(const uint4*)p;
    return r.v;
}

__device__ __forceinline__ float fast_tanh(float x) {
    float xc = fminf(fmaxf(x, -15.f), 15.f);
    float t = __expf(2.f * xc);
    return (t - 1.f) / (t + 1.f);
}

// ---------------------------------------------------------------------------
// Kernel 0 (fused prep): blocks 0..15 build Wtf in FRAGMENT-MAJOR layout:
// tile (n16 0..15, ks 0..15) is 64 lanes x 8 bf16 (1 KB), lane-major, so a
// wave's MFMA B-fragment load is one fully-coalesced 1-KB global read.
// Element: Wtf[((n16*16+ks)*64 + lane)*8 + j] = bf16(W[ks*32+(lane>>4)*8+j][n16*16+(lane&15)]).
// Blocks 16..47 compute qh[b] = bias + qry[b]@W_qry.
// ---------------------------------------------------------------------------
__global__ __launch_bounds__(256) void prep_kernel(
    const float* __restrict__ W, const float* __restrict__ qry,
    const float* __restrict__ bias, unsigned short* __restrict__ Wtf,
    float* __restrict__ qh) {
    __shared__ float q[QD_];
    const int bid = blockIdx.x;
    const int t = threadIdx.x;
    if (bid < 16) {
        const int n16 = bid;
        const int lane = t & 63;
        const int ksl = t >> 6;
        const int ncol = n16 * 16 + (lane & 15);
        #pragma unroll
        for (int r = 0; r < 4; ++r) {
            const int ks = ksl + r * 4;
            const int krow = ks * 32 + (lane >> 4) * 8;
            const float* src = W + (size_t)krow * ATTD_ + ncol;
            uint4 o;
            o.x = pk2(src[0], src[ATTD_]);
            o.y = pk2(src[2 * ATTD_], src[3 * ATTD_]);
            o.z = pk2(src[4 * ATTD_], src[5 * ATTD_]);
            o.w = pk2(src[6 * ATTD_], src[7 * ATTD_]);
            *(uint4*)(Wtf + ((size_t)(n16 * 16 + ks) * 64 + lane) * 8) = o;
        }
    } else {
        const int b = bid - 16;
        for (int i = t; i < QD_; i += 256) q[i] = qry[b * QD_ + i];
        __syncthreads();
        float acc = bias[t];
        const float* Wq = W + (size_t)CTXD_ * ATTD_ + t;
        #pragma unroll 8
        for (int k = 0; k < QD_; ++k) acc += q[k] * Wq[(size_t)k * ATTD_];
        qh[b * ATTD_ + t] = acc;
    }
}

// ---------------------------------------------------------------------------
// Kernel 1: BARRIER-FREE MFMA scores + fused local-softmax partial summary.
// No LDS staging at all: A fragments loaded per-lane from ctx (fp32 ->
// in-register bf16 cvt), B fragments loaded per-lane from fragment-major Wtf
// (L2-resident, 1-KB coalesced per wave-op). K loop is pure
// load->cvt->mfma dataflow, fully unrolled — the compiler pipelines loads
// across iterations and 8 free-running waves/CU hide latency via TLP
// (no vmcnt(0)+barrier lockstep). ctx read from HBM exactly once.
// ---------------------------------------------------------------------------
__global__ __launch_bounds__(256, 2) void scores_kernel(
    const float* __restrict__ ctx, const unsigned short* __restrict__ Wtf,
    const float* __restrict__ qh, const float* __restrict__ w2,
    const float* __restrict__ b2, const int* __restrict__ mask,
    float* __restrict__ scores, float* __restrict__ mstat,
    float* __restrict__ lstat, float* __restrict__ part) {
    __shared__ float sred[128];
    __shared__ float wl[64];
    __shared__ float4 pbuf[512];
    const int t = threadIdx.x;
    const int b = blockIdx.y;
    const int ch = blockIdx.x;
    const int s0 = ch * RT;
    const int tx = t & 63;  // lane
    const int w = t >> 6;   // wave
    const int wm = w & 1;   // M half: rows wm*32..+32
    const int wn = w >> 1;  // N half: cols wn*128..+128
    const int frow = tx & 15;
    const int fq = tx >> 4;  // 0..3

    f32x4 c00, c01, c02, c03, c04, c05, c06, c07;
    f32x4 c10, c11, c12, c13, c14, c15, c16, c17;
    c00 = c01 = c02 = c03 = c04 = c05 = c06 = c07 = (f32x4)0.f;
    c10 = c11 = c12 = c13 = c14 = c15 = c16 = c17 = (f32x4)0.f;

    const float* ctxb = ctx + ((size_t)b * S_ + s0) * CTXD_;
    // A fragment rows for this lane: (wm*32 + frow) and +16; k offset fq*8
    const float* aR0 = ctxb + (size_t)(wm * 32 + frow) * CTXD_ + fq * 8;
    const float* aR1 = aR0 + (size_t)16 * CTXD_;
    // B fragment base for this lane: wn-half of Wtf, lane-major tiles
    const unsigned short* bB = Wtf + ((size_t)(wn * 8) * 16 * 64 + tx) * 8;

#define MM1(ni, ks)                                                          \
    {                                                                        \
        bf16x8 bf = ld_bf8(bB + ((size_t)((ni) * 16 + (ks)) * 64) * 8);      \
        c0##ni = __builtin_amdgcn_mfma_f32_16x16x32_bf16(a0, bf, c0##ni, 0, 0, 0); \
        c1##ni = __builtin_amdgcn_mfma_f32_16x16x32_bf16(a1, bf, c1##ni, 0, 0, 0); \
    }
#define MMK(ks)                                                              \
    {                                                                        \
        float4 q0 = *(const float4*)(aR0 + (ks) * 32);                       \
        float4 q1 = *(const float4*)(aR0 + (ks) * 32 + 4);                   \
        float4 q2 = *(const float4*)(aR1 + (ks) * 32);                       \
        float4 q3 = *(const float4*)(aR1 + (ks) * 32 + 4);                   \
        bf16x8 a0 = cvt8(q0, q1);                                            \
        bf16x8 a1 = cvt8(q2, q3);                                            \
        MM1(0, ks) MM1(1, ks) MM1(2, ks) MM1(3, ks)                          \
        MM1(4, ks) MM1(5, ks) MM1(6, ks) MM1(7, ks)                          \
    }
    MMK(0)  MMK(1)  MMK(2)  MMK(3)
    MMK(4)  MMK(5)  MMK(6)  MMK(7)
    MMK(8)  MMK(9)  MMK(10) MMK(11)
    MMK(12) MMK(13) MMK(14) MMK(15)
#undef MMK
#undef MM1

    // Epilogue: lane holds D[row = wm*32 + mi*16 + fq*4 + r][col = wn*128 + ni*16 + frow]
    const float* qhb = qh + b * ATTD_ + wn * 128;
    const float* w2b = w2 + wn * 128;
    float p00 = 0.f, p01 = 0.f, p02 = 0.f, p03 = 0.f;
    float p10 = 0.f, p11 = 0.f, p12 = 0.f, p13 = 0.f;
#define EPI(ni)                                                              \
    {                                                                        \
        float qv = qhb[(ni) * 16 + frow];                                    \
        float wv = w2b[(ni) * 16 + frow];                                    \
        p00 += fast_tanh(c0##ni[0] + qv) * wv;                               \
        p01 += fast_tanh(c0##ni[1] + qv) * wv;                               \
        p02 += fast_tanh(c0##ni[2] + qv) * wv;                               \
        p03 += fast_tanh(c0##ni[3] + qv) * wv;                               \
        p10 += fast_tanh(c1##ni[0] + qv) * wv;                               \
        p11 += fast_tanh(c1##ni[1] + qv) * wv;                               \
        p12 += fast_tanh(c1##ni[2] + qv) * wv;                               \
        p13 += fast_tanh(c1##ni[3] + qv) * wv;                               \
    }
    EPI(0) EPI(1) EPI(2) EPI(3) EPI(4) EPI(5) EPI(6) EPI(7)
#undef EPI
    // reduce across the 16 frow lanes
    #pragma unroll
    for (int off = 1; off <= 8; off <<= 1) {
        p00 += __shfl_xor(p00, off, 64);
        p01 += __shfl_xor(p01, off, 64);
        p02 += __shfl_xor(p02, off, 64);
        p03 += __shfl_xor(p03, off, 64);
        p10 += __shfl_xor(p10, off, 64);
        p11 += __shfl_xor(p11, off, 64);
        p12 += __shfl_xor(p12, off, 64);
        p13 += __shfl_xor(p13, off, 64);
    }
    if (frow == 0) {
        const int base = wn * 64 + wm * 32 + fq * 4;
        sred[base + 0] = p00; sred[base + 1] = p01;
        sred[base + 2] = p02; sred[base + 3] = p03;
        sred[base + 16 + 0] = p10; sred[base + 16 + 1] = p11;
        sred[base + 16 + 2] = p12; sred[base + 16 + 3] = p13;
    }
    __syncthreads();
    // --- local softmax over this block's 64 rows (wave 0 only) ---
    if (t < 64) {
        const int s = s0 + t;
        float sc = sred[t] + sred[64 + t] + b2[0];
        const bool msk = (mask[b * S_ + s] == 0);
        if (msk) sc = MASKED_SCORE;
        scores[b * S_ + s] = sc;
        float mloc = sc;
        #pragma unroll
        for (int off = 1; off < 64; off <<= 1)
            mloc = fmaxf(mloc, __shfl_xor(mloc, off, 64));
        const float ws = msk ? 0.f : __expf(sc - mloc);
        float lloc = ws;
        #pragma unroll
        for (int off = 1; off < 64; off <<= 1)
            lloc += __shfl_xor(lloc, off, 64);
        if (t == 0) {
            mstat[b * NCH + ch] = mloc;
            lstat[b * NCH + ch] = lloc;
        }
        wl[t] = ws;
    }
    __syncthreads();
    // --- partial summary: Σ_s w_s · ctx[s,:]  (ctx rows are L2-hot) ---
    const int col = t & 63;  // float4 col idx (cols col and col+64)
    const int q = t >> 6;    // s ≡ q (mod 4)
    float4 alo = make_float4(0.f, 0.f, 0.f, 0.f);
    float4 ahi = make_float4(0.f, 0.f, 0.f, 0.f);
    #pragma unroll 4
    for (int s = q; s < RT; s += 4) {
        const float al = wl[s];
        const float4* row = (const float4*)(ctxb + (size_t)s * CTXD_);
        float4 v0 = row[col];
        float4 v1 = row[col + 64];
        alo.x += v0.x * al; alo.y += v0.y * al;
        alo.z += v0.z * al; alo.w += v0.w * al;
        ahi.x += v1.x * al; ahi.y += v1.y * al;
        ahi.z += v1.z * al; ahi.w += v1.w * al;
    }
    pbuf[q * 128 + col] = alo;
    pbuf[q * 128 + col + 64] = ahi;
    __syncthreads();
    if (t < 128) {
        float4 a0 = pbuf[t], a1 = pbuf[128 + t], a2 = pbuf[256 + t], a3 = pbuf[384 + t];
        float4 r;
        r.x = a0.x + a1.x + a2.x + a3.x;
        r.y = a0.y + a1.y + a2.y + a3.y;
        r.z = a0.z + a1.z + a2.z + a3.z;
        r.w = a0.w + a1.w + a2.w + a3.w;
        ((float4*)(part + ((size_t)(b * NCH + ch)) * CTXD_))[t] = r;
    }
}

// ---------------------------------------------------------------------------
// Kernel 2: combine — grid (4, B). Each block redoes the cheap per-chunk
// stats reduce (NCH=64), then handles a 128-col slice of summary and a
// 1024-row slice of alphas.
// ---------------------------------------------------------------------------
__global__ __launch_bounds__(256) void combine_kernel(
    const float* __restrict__ mstat, const float* __restrict__ lstat,
    const float* __restrict__ part, const float* __restrict__ scores,
    float* __restrict__ alphas, float* __restrict__ summary) {
    const int b = blockIdx.y, seg = blockIdx.x, t = threadIdx.x;
    __shared__ float e[NCH];
    __shared__ float gstat[2];  // m, invl
    if (t < NCH) {
        const float mi = mstat[b * NCH + t];
        const float li = lstat[b * NCH + t];
        float m = mi;
        #pragma unroll
        for (int off = 1; off < 64; off <<= 1)
            m = fmaxf(m, __shfl_xor(m, off, 64));
        const float ei = __expf(mi - m);  // all-masked chunk: underflows to 0
        float l = ei * li;
        #pragma unroll
        for (int off = 1; off < 64; off <<= 1)
            l += __shfl_xor(l, off, 64);
        e[t] = ei;
        if (t == 0) { gstat[0] = m; gstat[1] = 1.0f / l; }
    }
    __syncthreads();
    const float m = gstat[0], il = gstat[1];
    // summary slice: cols [seg*128, seg*128+128) = 32 float4
    const int c4 = t & 31;   // float4 within slice
    const int grp = t >> 5;  // 0..7: chunk phase
    float4 acc = make_float4(0.f, 0.f, 0.f, 0.f);
    for (int chv = grp; chv < NCH; chv += 8) {
        const float ei = e[chv];
        float4 v =
            ((const float4*)(part + ((size_t)(b * NCH + chv)) * CTXD_ + seg * 128))[c4];
        acc.x += ei * v.x; acc.y += ei * v.y;
        acc.z += ei * v.z; acc.w += ei * v.w;
    }
    __shared__ float4 buf[8][32];
    buf[grp][c4] = acc;
    __syncthreads();
    if (t < 32) {
        float4 r = make_float4(0.f, 0.f, 0.f, 0.f);
        #pragma unroll
        for (int g = 0; g < 8; ++g) {
            float4 v = buf[g][t];
            r.x += v.x; r.y += v.y; r.z += v.z; r.w += v.w;
        }
        r.x *= il; r.y *= il; r.z *= il; r.w *= il;
        ((float4*)(summary + (size_t)b * CTXD_ + seg * 128))[t] = r;
    }
    // alphas slice: s in [seg*1024, +1024)
    const int sbase = seg * 1024;
    #pragma unroll
    for (int i = 0; i < 4; ++i) {
        const int s = sbase + i * 256 + t;
        alphas[b * S_ + s] = __expf(scores[b * S_ + s] - m) * il;
    }
}

extern "C" void kernel_launch(void* const* d_in, const int* in_sizes, int n_in,
                              void* d_out, int out_size, void* d_ws,
                              size_t ws_size, hipStream_t stream) {
    const float* qry = (const float*)d_in[0];
    const float* ctx = (const float*)d_in[1];
    const int* mask = (const int*)d_in[2];
    const float* W = (const float*)d_in[3];
    const float* bias = (const float*)d_in[4];
    const float* w2 = (const float*)d_in[5];
    const float* b2 = (const float*)d_in[6];

    float* out = (float*)d_out;
    float* alphas = out;                         // B*S
    float* summary = out + B_ * S_;              // B*CTXD
    float* scores = out + B_ * S_ + B_ * CTXD_;  // B*S

    // ws layout: [Wtf bf16 256KB][qh 32KB][mstat 8KB][lstat 8KB][part 4MB]
    unsigned short* Wtf = (unsigned short*)d_ws;
    float* qh = (float*)((char*)d_ws + (size_t)ATTD_ * CTXD_ * 2);
    float* mstat = qh + B_ * ATTD_;
    float* lstat = mstat + B_ * NCH;
    float* part = lstat + B_ * NCH;

    prep_kernel<<<48, 256, 0, stream>>>(W, qry, bias, Wtf, qh);
    scores_kernel<<<dim3(NCH, B_), 256, 0, stream>>>(ctx, Wtf, qh, w2, b2, mask,
                                                     scores, mstat, lstat, part);
    combine_kernel<<<dim3(4, B_), 256, 0, stream>>>(mstat, lstat, part, scores,
                                                    alphas, summary);
}

// Round 11
// 476.469 us; speedup vs baseline: 1.1761x; 1.1761x over previous
//
#include <hip/hip_runtime.h>
#include <math.h>

#define B_ 32
#define S_ 4096
#define CTXD_ 512
#define QD_ 512
#define ATTD_ 256

#define RT 64          // rows (s) per block
#define NCH (S_ / RT)  // 64 chunks per batch row

#define MASKED_SCORE (-1e30f)

// LDS double-buffer offsets (A: 64 rows x 80B; B: 256 rows x 80B)
#define AOFF0 0
#define AOFF1 5120
#define BOFF0 10240
#define BOFF1 30720
#define LDS_BYTES 51200

typedef __attribute__((ext_vector_type(8))) short bf16x8;   // 8 bf16 = 4 VGPR
typedef __attribute__((ext_vector_type(4))) float f32x4;    // MFMA C/D

// fp32 -> bf16 round-to-nearest-even (inputs are finite randoms)
__device__ __forceinline__ unsigned short f2bf(float f) {
    unsigned u = __float_as_uint(f);
    u += 0x7fff + ((u >> 16) & 1);
    return (unsigned short)(u >> 16);
}
__device__ __forceinline__ unsigned pk2(float lo, float hi) {
    return (unsigned)f2bf(lo) | ((unsigned)f2bf(hi) << 16);
}

__device__ __forceinline__ float fast_tanh(float x) {
    float xc = fminf(fmaxf(x, -15.f), 15.f);
    float t = __expf(2.f * xc);
    return (t - 1.f) / (t + 1.f);
}

// ---------------------------------------------------------------------------
// Kernel 0 (fused prep): blocks 0..31 transpose+convert W_ctx -> Wt bf16
// (64x64 tiles); blocks 32..63 compute qh[b] = bias + qry[b]@W_qry.
// ---------------------------------------------------------------------------
__global__ __launch_bounds__(256) void prep_kernel(
    const float* __restrict__ W, const float* __restrict__ qry,
    const float* __restrict__ bias, unsigned short* __restrict__ Wt,
    float* __restrict__ qh) {
    __shared__ unsigned char lds[64 * 66 * 2];  // wt tile (8448 B) / qh q (2048 B)
    const int bid = blockIdx.x;
    const int t = threadIdx.x;
    if (bid < 32) {
        unsigned short(*tile)[66] = (unsigned short(*)[66])lds;
        const int kk = (bid >> 2) * 64;
        const int nn = (bid & 3) * 64;
        #pragma unroll
        for (int i = 0; i < 4; ++i) {
            const int r = i * 16 + (t >> 4);
            float4 v = ((const float4*)(W + (size_t)(kk + r) * ATTD_ + nn))[t & 15];
            unsigned short* tr = &tile[r][(t & 15) * 4];
            tr[0] = f2bf(v.x); tr[1] = f2bf(v.y);
            tr[2] = f2bf(v.z); tr[3] = f2bf(v.w);
        }
        __syncthreads();
        const int l8 = (t & 7) * 8;
        #pragma unroll
        for (int p = 0; p < 2; ++p) {
            const int n = p * 32 + (t >> 3);
            uint4 o;
            o.x = (unsigned)tile[l8 + 0][n] | ((unsigned)tile[l8 + 1][n] << 16);
            o.y = (unsigned)tile[l8 + 2][n] | ((unsigned)tile[l8 + 3][n] << 16);
            o.z = (unsigned)tile[l8 + 4][n] | ((unsigned)tile[l8 + 5][n] << 16);
            o.w = (unsigned)tile[l8 + 6][n] | ((unsigned)tile[l8 + 7][n] << 16);
            *(uint4*)(Wt + (size_t)(nn + n) * CTXD_ + kk + l8) = o;
        }
    } else {
        float* q = (float*)lds;
        const int b = bid - 32;
        for (int i = t; i < QD_; i += 256) q[i] = qry[b * QD_ + i];
        __syncthreads();
        float acc = bias[t];
        const float* Wq = W + (size_t)CTXD_ * ATTD_ + t;
        #pragma unroll 8
        for (int k = 0; k < QD_; ++k) acc += q[k] * Wq[(size_t)k * ATTD_];
        qh[b * ATTD_ + t] = acc;
    }
}

// ---------------------------------------------------------------------------
// Kernel 1: MFMA scores + fused local-softmax partial summary, with a
// COUNTED-WAIT PIPELINE: double-buffered LDS (2x25.6KB -> 3 blocks/CU),
// depth-2 register prefetch, raw s_barrier + lgkmcnt(0) only (NO
// __syncthreads in the K-loop -> no vmcnt(0) drain; compiler emits counted
// vmcnt for the reg-staged loads, so the younger prefetch set stays in
// flight across barriers). 16 K-tiles of 32, one barrier each.
// ---------------------------------------------------------------------------
__global__ __launch_bounds__(256, 3) void scores_kernel(
    const float* __restrict__ ctx, const unsigned short* __restrict__ Wt,
    const float* __restrict__ qh, const float* __restrict__ w2,
    const float* __restrict__ b2, const int* __restrict__ mask,
    float* __restrict__ scores, float* __restrict__ mstat,
    float* __restrict__ lstat, float* __restrict__ part) {
    __shared__ __attribute__((aligned(16))) unsigned char lds[LDS_BYTES];
    const int t = threadIdx.x;
    const int b = blockIdx.y;
    const int ch = blockIdx.x;
    const int s0 = ch * RT;
    const int tx = t & 63;  // lane
    const int w = t >> 6;   // wave
    const int wm = w & 1;   // M half: rows wm*32..+32
    const int wn = w >> 1;  // N half: cols wn*128..+128
    const int frow = tx & 15;
    const int fq = tx >> 4;  // 0..3

    f32x4 c00, c01, c02, c03, c04, c05, c06, c07;
    f32x4 c10, c11, c12, c13, c14, c15, c16, c17;
    c00 = c01 = c02 = c03 = c04 = c05 = c06 = c07 = (f32x4)0.f;
    c10 = c11 = c12 = c13 = c14 = c15 = c16 = c17 = (f32x4)0.f;

    const float* ctxb = ctx + ((size_t)b * S_ + s0) * CTXD_;
    const int arow = t >> 2;  // A staging row 0..63
    const int akq = t & 3;    // 8-col group of the 32-k tile
    const int bn = t;         // B staging row 0..255

    // two named prefetch register sets (rule #20: no runtime-indexed arrays)
    float4 fa0_0, fa1_0, fa0_1, fa1_1;
    uint4 pb0_0, pb1_0, pb2_0, pb3_0;
    uint4 pb0_1, pb1_1, pb2_1, pb3_1;

#define ISSUE(S, kk)                                                         \
    {                                                                        \
        const float* ap = ctxb + (size_t)arow * CTXD_ + (kk) * 32 + akq * 8; \
        fa0_##S = ((const float4*)ap)[0];                                    \
        fa1_##S = ((const float4*)ap)[1];                                    \
        const uint4* bp = (const uint4*)(Wt + (size_t)bn * CTXD_ + (kk) * 32); \
        pb0_##S = bp[0]; pb1_##S = bp[1]; pb2_##S = bp[2]; pb3_##S = bp[3];  \
    }
#define WRITE(S, P)                                                          \
    {                                                                        \
        uint4 wv;                                                            \
        wv.x = pk2(fa0_##S.x, fa0_##S.y); wv.y = pk2(fa0_##S.z, fa0_##S.w);  \
        wv.z = pk2(fa1_##S.x, fa1_##S.y); wv.w = pk2(fa1_##S.z, fa1_##S.w);  \
        *(uint4*)(lds + AOFF##P + arow * 80 + akq * 16) = wv;                \
        uint4* bw = (uint4*)(lds + BOFF##P + bn * 80);                       \
        bw[0] = pb0_##S; bw[1] = pb1_##S; bw[2] = pb2_##S; bw[3] = pb3_##S;  \
    }
#define MM1(ni, P)                                                           \
    {                                                                        \
        bf16x8 bf = *(const bf16x8*)(lds + BOFF##P +                         \
                                     (wn * 128 + (ni) * 16 + frow) * 80 +    \
                                     fq * 16);                               \
        c0##ni = __builtin_amdgcn_mfma_f32_16x16x32_bf16(a0, bf, c0##ni, 0, 0, 0); \
        c1##ni = __builtin_amdgcn_mfma_f32_16x16x32_bf16(a1, bf, c1##ni, 0, 0, 0); \
    }
#define COMPUTE(P)                                                           \
    {                                                                        \
        const unsigned char* aB = lds + AOFF##P + (wm * 32 + frow) * 80 + fq * 16; \
        bf16x8 a0 = *(const bf16x8*)aB;                                      \
        bf16x8 a1 = *(const bf16x8*)(aB + 16 * 80);                          \
        MM1(0, P) MM1(1, P) MM1(2, P) MM1(3, P)                              \
        MM1(4, P) MM1(5, P) MM1(6, P) MM1(7, P)                              \
    }
#define BAR                                                                  \
    asm volatile("s_waitcnt lgkmcnt(0)" ::: "memory");                       \
    __builtin_amdgcn_s_barrier();                                            \
    __builtin_amdgcn_sched_barrier(0);

    // prologue: T0,T1 in flight; stage T0; T2 in flight
    ISSUE(0, 0) ISSUE(1, 1)
    WRITE(0, 0) ISSUE(0, 2)
    BAR
    // iter k: stage T(k+1) -> buf[(k+1)&1]; issue T(k+3); compute T(k)
    WRITE(1, 1) ISSUE(1, 3)  COMPUTE(0) BAR   // k=0
    WRITE(0, 0) ISSUE(0, 4)  COMPUTE(1) BAR   // k=1
    WRITE(1, 1) ISSUE(1, 5)  COMPUTE(0) BAR   // k=2
    WRITE(0, 0) ISSUE(0, 6)  COMPUTE(1) BAR   // k=3
    WRITE(1, 1) ISSUE(1, 7)  COMPUTE(0) BAR   // k=4
    WRITE(0, 0) ISSUE(0, 8)  COMPUTE(1) BAR   // k=5
    WRITE(1, 1) ISSUE(1, 9)  COMPUTE(0) BAR   // k=6
    WRITE(0, 0) ISSUE(0, 10) COMPUTE(1) BAR   // k=7
    WRITE(1, 1) ISSUE(1, 11) COMPUTE(0) BAR   // k=8
    WRITE(0, 0) ISSUE(0, 12) COMPUTE(1) BAR   // k=9
    WRITE(1, 1) ISSUE(1, 13) COMPUTE(0) BAR   // k=10
    WRITE(0, 0) ISSUE(0, 14) COMPUTE(1) BAR   // k=11
    WRITE(1, 1) ISSUE(1, 15) COMPUTE(0) BAR   // k=12
    WRITE(0, 0)              COMPUTE(1) BAR   // k=13
    WRITE(1, 1)              COMPUTE(0) BAR   // k=14
    COMPUTE(1)                                // k=15
#undef BAR
#undef COMPUTE
#undef MM1
#undef WRITE
#undef ISSUE

    // Epilogue: lane holds D[row = wm*32 + fq*4 + r (+16 for c1)][col = wn*128 + ni*16 + frow]
    const float* qhb = qh + b * ATTD_ + wn * 128;
    const float* w2b = w2 + wn * 128;
    float p00 = 0.f, p01 = 0.f, p02 = 0.f, p03 = 0.f;
    float p10 = 0.f, p11 = 0.f, p12 = 0.f, p13 = 0.f;
#define EPI(ni)                                                              \
    {                                                                        \
        float qv = qhb[(ni) * 16 + frow];                                    \
        float wv = w2b[(ni) * 16 + frow];                                    \
        p00 += fast_tanh(c0##ni[0] + qv) * wv;                               \
        p01 += fast_tanh(c0##ni[1] + qv) * wv;                               \
        p02 += fast_tanh(c0##ni[2] + qv) * wv;                               \
        p03 += fast_tanh(c0##ni[3] + qv) * wv;                               \
        p10 += fast_tanh(c1##ni[0] + qv) * wv;                               \
        p11 += fast_tanh(c1##ni[1] + qv) * wv;                               \
        p12 += fast_tanh(c1##ni[2] + qv) * wv;                               \
        p13 += fast_tanh(c1##ni[3] + qv) * wv;                               \
    }
    EPI(0) EPI(1) EPI(2) EPI(3) EPI(4) EPI(5) EPI(6) EPI(7)
#undef EPI
    #pragma unroll
    for (int off = 1; off <= 8; off <<= 1) {
        p00 += __shfl_xor(p00, off, 64);
        p01 += __shfl_xor(p01, off, 64);
        p02 += __shfl_xor(p02, off, 64);
        p03 += __shfl_xor(p03, off, 64);
        p10 += __shfl_xor(p10, off, 64);
        p11 += __shfl_xor(p11, off, 64);
        p12 += __shfl_xor(p12, off, 64);
        p13 += __shfl_xor(p13, off, 64);
    }
    // reuse the K-loop LDS for the reductions
    float* sred = (float*)lds;            // 128 floats
    float* wl = (float*)(lds + 512);      // 64 floats
    float4* pbuf = (float4*)(lds + 1024); // 512 float4
    __syncthreads();  // all K-loop LDS traffic done everywhere
    if (frow == 0) {
        const int base = wn * 64 + wm * 32 + fq * 4;
        sred[base + 0] = p00; sred[base + 1] = p01;
        sred[base + 2] = p02; sred[base + 3] = p03;
        sred[base + 16 + 0] = p10; sred[base + 16 + 1] = p11;
        sred[base + 16 + 2] = p12; sred[base + 16 + 3] = p13;
    }
    __syncthreads();
    // --- local softmax over this block's 64 rows (wave 0 only) ---
    if (t < 64) {
        const int s = s0 + t;
        float sc = sred[t] + sred[64 + t] + b2[0];
        const bool msk = (mask[b * S_ + s] == 0);
        if (msk) sc = MASKED_SCORE;
        scores[b * S_ + s] = sc;
        float mloc = sc;
        #pragma unroll
        for (int off = 1; off < 64; off <<= 1)
            mloc = fmaxf(mloc, __shfl_xor(mloc, off, 64));
        const float ws = msk ? 0.f : __expf(sc - mloc);
        float lloc = ws;
        #pragma unroll
        for (int off = 1; off < 64; off <<= 1)
            lloc += __shfl_xor(lloc, off, 64);
        if (t == 0) {
            mstat[b * NCH + ch] = mloc;
            lstat[b * NCH + ch] = lloc;
        }
        wl[t] = ws;
    }
    __syncthreads();
    // --- partial summary: Σ_s w_s · ctx[s,:]  (ctx rows are L2-hot) ---
    const int col = t & 63;  // float4 col idx (cols col and col+64)
    const int q = t >> 6;    // s ≡ q (mod 4)
    float4 alo = make_float4(0.f, 0.f, 0.f, 0.f);
    float4 ahi = make_float4(0.f, 0.f, 0.f, 0.f);
    #pragma unroll 4
    for (int s = q; s < RT; s += 4) {
        const float al = wl[s];
        const float4* row = (const float4*)(ctxb + (size_t)s * CTXD_);
        float4 v0 = row[col];
        float4 v1 = row[col + 64];
        alo.x += v0.x * al; alo.y += v0.y * al;
        alo.z += v0.z * al; alo.w += v0.w * al;
        ahi.x += v1.x * al; ahi.y += v1.y * al;
        ahi.z += v1.z * al; ahi.w += v1.w * al;
    }
    pbuf[q * 128 + col] = alo;
    pbuf[q * 128 + col + 64] = ahi;
    __syncthreads();
    if (t < 128) {
        float4 a0 = pbuf[t], a1 = pbuf[128 + t], a2 = pbuf[256 + t], a3 = pbuf[384 + t];
        float4 r;
        r.x = a0.x + a1.x + a2.x + a3.x;
        r.y = a0.y + a1.y + a2.y + a3.y;
        r.z = a0.z + a1.z + a2.z + a3.z;
        r.w = a0.w + a1.w + a2.w + a3.w;
        ((float4*)(part + ((size_t)(b * NCH + ch)) * CTXD_))[t] = r;
    }
}

// ---------------------------------------------------------------------------
// Kernel 2: combine — grid (4, B). Each block redoes the cheap per-chunk
// stats reduce (NCH=64), then handles a 128-col slice of summary and a
// 1024-row slice of alphas.
// ---------------------------------------------------------------------------
__global__ __launch_bounds__(256) void combine_kernel(
    const float* __restrict__ mstat, const float* __restrict__ lstat,
    const float* __restrict__ part, const float* __restrict__ scores,
    float* __restrict__ alphas, float* __restrict__ summary) {
    const int b = blockIdx.y, seg = blockIdx.x, t = threadIdx.x;
    __shared__ float e[NCH];
    __shared__ float gstat[2];  // m, invl
    if (t < NCH) {
        const float mi = mstat[b * NCH + t];
        const float li = lstat[b * NCH + t];
        float m = mi;
        #pragma unroll
        for (int off = 1; off < 64; off <<= 1)
            m = fmaxf(m, __shfl_xor(m, off, 64));
        const float ei = __expf(mi - m);  // all-masked chunk: underflows to 0
        float l = ei * li;
        #pragma unroll
        for (int off = 1; off < 64; off <<= 1)
            l += __shfl_xor(l, off, 64);
        e[t] = ei;
        if (t == 0) { gstat[0] = m; gstat[1] = 1.0f / l; }
    }
    __syncthreads();
    const float m = gstat[0], il = gstat[1];
    // summary slice: cols [seg*128, seg*128+128) = 32 float4
    const int c4 = t & 31;   // float4 within slice
    const int grp = t >> 5;  // 0..7: chunk phase
    float4 acc = make_float4(0.f, 0.f, 0.f, 0.f);
    for (int chv = grp; chv < NCH; chv += 8) {
        const float ei = e[chv];
        float4 v =
            ((const float4*)(part + ((size_t)(b * NCH + chv)) * CTXD_ + seg * 128))[c4];
        acc.x += ei * v.x; acc.y += ei * v.y;
        acc.z += ei * v.z; acc.w += ei * v.w;
    }
    __shared__ float4 buf[8][32];
    buf[grp][c4] = acc;
    __syncthreads();
    if (t < 32) {
        float4 r = make_float4(0.f, 0.f, 0.f, 0.f);
        #pragma unroll
        for (int g = 0; g < 8; ++g) {
            float4 v = buf[g][t];
            r.x += v.x; r.y += v.y; r.z += v.z; r.w += v.w;
        }
        r.x *= il; r.y *= il; r.z *= il; r.w *= il;
        ((float4*)(summary + (size_t)b * CTXD_ + seg * 128))[t] = r;
    }
    // alphas slice: s in [seg*1024, +1024)
    const int sbase = seg * 1024;
    #pragma unroll
    for (int i = 0; i < 4; ++i) {
        const int s = sbase + i * 256 + t;
        alphas[b * S_ + s] = __expf(scores[b * S_ + s] - m) * il;
    }
}

extern "C" void kernel_launch(void* const* d_in, const int* in_sizes, int n_in,
                              void* d_out, int out_size, void* d_ws,
                              size_t ws_size, hipStream_t stream) {
    const float* qry = (const float*)d_in[0];
    const float* ctx = (const float*)d_in[1];
    const int* mask = (const int*)d_in[2];
    const float* W = (const float*)d_in[3];
    const float* bias = (const float*)d_in[4];
    const float* w2 = (const float*)d_in[5];
    const float* b2 = (const float*)d_in[6];

    float* out = (float*)d_out;
    float* alphas = out;                         // B*S
    float* summary = out + B_ * S_;              // B*CTXD
    float* scores = out + B_ * S_ + B_ * CTXD_;  // B*S

    // ws layout: [Wt bf16 256KB][qh 32KB][mstat 8KB][lstat 8KB][part 4MB]
    unsigned short* Wt = (unsigned short*)d_ws;
    float* qh = (float*)((char*)d_ws + (size_t)ATTD_ * CTXD_ * 2);
    float* mstat = qh + B_ * ATTD_;
    float* lstat = mstat + B_ * NCH;
    float* part = lstat + B_ * NCH;

    prep_kernel<<<64, 256, 0, stream>>>(W, qry, bias, Wt, qh);
    scores_kernel<<<dim3(NCH, B_), 256, 0, stream>>>(ctx, Wt, qh, w2, b2, mask,
                                                     scores, mstat, lstat, part);
    combine_kernel<<<dim3(4, B_), 256, 0, stream>>>(mstat, lstat, part, scores,
                                                    alphas, summary);
}

// Round 13
// 461.849 us; speedup vs baseline: 1.2134x; 1.0317x over previous
//
#include <hip/hip_runtime.h>
#include <math.h>

#define B_ 32
#define S_ 4096
#define CTXD_ 512
#define QD_ 512
#define ATTD_ 256

#define RT 64          // rows (s) per block
#define NCH (S_ / RT)  // 64 chunks per batch row

#define MASKED_SCORE (-1e30f)

// LDS map: A dbuf 2 x (64 rows x 80B) ; B dbuf 2 x 16384B (256 rows x 64B)
#define AOFF0 0
#define AOFF1 5120
#define BOFF0 10240
#define BOFF1 26624
#define LDS_BYTES 43008

typedef __attribute__((ext_vector_type(8))) short bf16x8;   // 8 bf16 = 4 VGPR
typedef __attribute__((ext_vector_type(4))) float f32x4;    // MFMA C/D

// fp32 -> bf16 round-to-nearest-even (inputs are finite randoms)
__device__ __forceinline__ unsigned short f2bf(float f) {
    unsigned u = __float_as_uint(f);
    u += 0x7fff + ((u >> 16) & 1);
    return (unsigned short)(u >> 16);
}
__device__ __forceinline__ unsigned pk2(float lo, float hi) {
    return (unsigned)f2bf(lo) | ((unsigned)f2bf(hi) << 16);
}

__device__ __forceinline__ float fast_tanh(float x) {
    float xc = fminf(fmaxf(x, -15.f), 15.f);
    float t = __expf(2.f * xc);
    return (t - 1.f) / (t + 1.f);
}

// ---------------------------------------------------------------------------
// Kernel 0 (fused prep): blocks 0..31 build Wt_lin — k-tile-major LDS-image
// layout: tile kt (k = kt*32..+32) is [256 rows n][32 bf16], 16 KB, so the
// scores kernel can stage it with linear global_load_lds DMA.
//   Wt_lin[(kt*256 + n)*32 + kk] = bf16(W[kt*32 + kk][n])
// Blocks 32..63 compute qh[b] = bias + qry[b]@W_qry.
// ---------------------------------------------------------------------------
__global__ __launch_bounds__(256) void prep_kernel(
    const float* __restrict__ W, const float* __restrict__ qry,
    const float* __restrict__ bias, unsigned short* __restrict__ Wt_lin,
    float* __restrict__ qh) {
    __shared__ unsigned char lds[64 * 66 * 2];  // transpose tile / qh q-vector
    const int bid = blockIdx.x;
    const int t = threadIdx.x;
    if (bid < 32) {
        unsigned short(*tile)[66] = (unsigned short(*)[66])lds;
        const int kk = (bid >> 2) * 64;   // k-rows kk..kk+64 (k-tiles kt0, kt0+1)
        const int nn = (bid & 3) * 64;    // n-cols nn..nn+64
        #pragma unroll
        for (int i = 0; i < 4; ++i) {
            const int r = i * 16 + (t >> 4);
            float4 v = ((const float4*)(W + (size_t)(kk + r) * ATTD_ + nn))[t & 15];
            unsigned short* tr = &tile[r][(t & 15) * 4];
            tr[0] = f2bf(v.x); tr[1] = f2bf(v.y);
            tr[2] = f2bf(v.z); tr[3] = f2bf(v.w);
        }
        __syncthreads();
        const int kt0 = (bid >> 2) * 2;
        const int n = t & 63;        // local n
        const int q = t >> 6;        // k-quarter (8 values)
        #pragma unroll
        for (int kt_loc = 0; kt_loc < 2; ++kt_loc) {
            const int kbase = kt_loc * 32 + q * 8;
            uint4 o;
            o.x = (unsigned)tile[kbase + 0][n] | ((unsigned)tile[kbase + 1][n] << 16);
            o.y = (unsigned)tile[kbase + 2][n] | ((unsigned)tile[kbase + 3][n] << 16);
            o.z = (unsigned)tile[kbase + 4][n] | ((unsigned)tile[kbase + 5][n] << 16);
            o.w = (unsigned)tile[kbase + 6][n] | ((unsigned)tile[kbase + 7][n] << 16);
            *(uint4*)(Wt_lin + ((size_t)(kt0 + kt_loc) * 256 + nn + n) * 32 + q * 8) = o;
        }
    } else {
        float* q = (float*)lds;
        const int b = bid - 32;
        for (int i = t; i < QD_; i += 256) q[i] = qry[b * QD_ + i];
        __syncthreads();
        float acc = bias[t];
        const float* Wq = W + (size_t)CTXD_ * ATTD_ + t;
        #pragma unroll 8
        for (int k = 0; k < QD_; ++k) acc += q[k] * Wq[(size_t)k * ATTD_];
        qh[b * ATTD_ + t] = acc;
    }
}

// ---------------------------------------------------------------------------
// Kernel 1: MFMA scores + fused local-softmax partial summary.
// B staged by global_load_lds(16B) DMA from L2-resident Wt_lin (no VGPR
// round-trip, no ds_writes for B); A reg-staged fp32->bf16. Both
// double-buffered; m97-style 2-barrier K-step; next tile's loads issued
// AFTER the write barrier so they stay in flight across the compute phase.
// ---------------------------------------------------------------------------
__global__ __launch_bounds__(256, 3) void scores_kernel(
    const float* __restrict__ ctx, const unsigned short* __restrict__ Wt_lin,
    const float* __restrict__ qh, const float* __restrict__ w2,
    const float* __restrict__ b2, const int* __restrict__ mask,
    float* __restrict__ scores, float* __restrict__ mstat,
    float* __restrict__ lstat, float* __restrict__ part) {
    __shared__ __attribute__((aligned(16))) unsigned char lds[LDS_BYTES];
    const int t = threadIdx.x;
    const int b = blockIdx.y;
    const int ch = blockIdx.x;
    const int s0 = ch * RT;
    const int tx = t & 63;  // lane
    const int w = t >> 6;   // wave
    const int wm = w & 1;   // M half: rows wm*32..+32
    const int wn = w >> 1;  // N half: cols wn*128..+128
    const int frow = tx & 15;
    const int fq = tx >> 4;  // 0..3

    f32x4 c00, c01, c02, c03, c04, c05, c06, c07;
    f32x4 c10, c11, c12, c13, c14, c15, c16, c17;
    c00 = c01 = c02 = c03 = c04 = c05 = c06 = c07 = (f32x4)0.f;
    c10 = c11 = c12 = c13 = c14 = c15 = c16 = c17 = (f32x4)0.f;

    const float* ctxb = ctx + ((size_t)b * S_ + s0) * CTXD_;
    const int arow = t >> 2;  // A staging row 0..63
    const int akq = t & 3;    // 8-float group of the 32-k tile

    // per-lane global source base for the B DMA (wave chunk + lane*16)
    const unsigned char* wtl =
        (const unsigned char*)Wt_lin + w * 4096 + tx * 16;

    float4 fa0, fa1;  // A prefetch registers (single named set)

#define ISSUE_A(kt)                                                          \
    {                                                                        \
        const float* ap = ctxb + (size_t)arow * CTXD_ + (kt) * 32 + akq * 8; \
        fa0 = ((const float4*)ap)[0];                                        \
        fa1 = ((const float4*)ap)[1];                                        \
    }
#define ISSUE_B(P, kt)                                                      \
    {                                                                       \
        _Pragma("unroll")                                                   \
        for (int i = 0; i < 4; ++i) {                                       \
            __builtin_amdgcn_global_load_lds(                               \
                (const __attribute__((address_space(1))) unsigned int*)     \
                    (wtl + (kt) * 16384 + i * 1024),                        \
                (__attribute__((address_space(3))) unsigned int*)           \
                    (lds + BOFF##P + w * 4096 + i * 1024),                  \
                16, 0, 0);                                                  \
        }                                                                   \
    }
#define WRITE_A(P)                                                          \
    {                                                                       \
        uint4 wv;                                                           \
        wv.x = pk2(fa0.x, fa0.y); wv.y = pk2(fa0.z, fa0.w);                 \
        wv.z = pk2(fa1.x, fa1.y); wv.w = pk2(fa1.z, fa1.w);                 \
        *(uint4*)(lds + AOFF##P + arow * 80 + akq * 16) = wv;               \
    }
#define MM1(ni, P)                                                           \
    {                                                                        \
        bf16x8 bf = *(const bf16x8*)(lds + BOFF##P +                         \
                                     (wn * 128 + (ni) * 16 + frow) * 64 +    \
                                     fq * 16);                               \
        c0##ni = __builtin_amdgcn_mfma_f32_16x16x32_bf16(a0, bf, c0##ni, 0, 0, 0); \
        c1##ni = __builtin_amdgcn_mfma_f32_16x16x32_bf16(a1, bf, c1##ni, 0, 0, 0); \
    }
#define COMPUTE(P)                                                           \
    {                                                                        \
        const unsigned char* aB = lds + AOFF##P + (wm * 32 + frow) * 80 + fq * 16; \
        bf16x8 a0 = *(const bf16x8*)aB;                                      \
        bf16x8 a1 = *(const bf16x8*)(aB + 16 * 80);                          \
        MM1(0, P) MM1(1, P) MM1(2, P) MM1(3, P)                              \
        MM1(4, P) MM1(5, P) MM1(6, P) MM1(7, P)                              \
    }
// iter k (buffer P=k&1): sync(a) [drains DMA Tk + A-regs Tk + prior reads];
// write A; sync(b) [A visible]; issue T(k+1) loads (stay in flight through
// compute, drained at next sync(a)); compute Tk.
#define STEP(P, PN, k)                                                      \
    __syncthreads();                                                        \
    WRITE_A(P)                                                              \
    __syncthreads();                                                        \
    ISSUE_B(PN, (k) + 1) ISSUE_A((k) + 1)                                   \
    COMPUTE(P)

    // prologue: tile 0 in flight
    ISSUE_B(0, 0) ISSUE_A(0)
    STEP(0, 1, 0)  STEP(1, 0, 1)  STEP(0, 1, 2)  STEP(1, 0, 3)
    STEP(0, 1, 4)  STEP(1, 0, 5)  STEP(0, 1, 6)  STEP(1, 0, 7)
    STEP(0, 1, 8)  STEP(1, 0, 9)  STEP(0, 1, 10) STEP(1, 0, 11)
    STEP(0, 1, 12) STEP(1, 0, 13) STEP(0, 1, 14)
    // k=15 (no further prefetch)
    __syncthreads();
    WRITE_A(1)
    __syncthreads();
    COMPUTE(1)
#undef STEP
#undef COMPUTE
#undef MM1
#undef WRITE_A
#undef ISSUE_B
#undef ISSUE_A

    // Epilogue: lane holds D[row = wm*32 + fq*4 + r (+16 for c1)][col = wn*128 + ni*16 + frow]
    const float* qhb = qh + b * ATTD_ + wn * 128;
    const float* w2b = w2 + wn * 128;
    float p00 = 0.f, p01 = 0.f, p02 = 0.f, p03 = 0.f;
    float p10 = 0.f, p11 = 0.f, p12 = 0.f, p13 = 0.f;
#define EPI(ni)                                                              \
    {                                                                        \
        float qv = qhb[(ni) * 16 + frow];                                    \
        float wv = w2b[(ni) * 16 + frow];                                    \
        p00 += fast_tanh(c0##ni[0] + qv) * wv;                               \
        p01 += fast_tanh(c0##ni[1] + qv) * wv;                               \
        p02 += fast_tanh(c0##ni[2] + qv) * wv;                               \
        p03 += fast_tanh(c0##ni[3] + qv) * wv;                               \
        p10 += fast_tanh(c1##ni[0] + qv) * wv;                               \
        p11 += fast_tanh(c1##ni[1] + qv) * wv;                               \
        p12 += fast_tanh(c1##ni[2] + qv) * wv;                               \
        p13 += fast_tanh(c1##ni[3] + qv) * wv;                               \
    }
    EPI(0) EPI(1) EPI(2) EPI(3) EPI(4) EPI(5) EPI(6) EPI(7)
#undef EPI
    #pragma unroll
    for (int off = 1; off <= 8; off <<= 1) {
        p00 += __shfl_xor(p00, off, 64);
        p01 += __shfl_xor(p01, off, 64);
        p02 += __shfl_xor(p02, off, 64);
        p03 += __shfl_xor(p03, off, 64);
        p10 += __shfl_xor(p10, off, 64);
        p11 += __shfl_xor(p11, off, 64);
        p12 += __shfl_xor(p12, off, 64);
        p13 += __shfl_xor(p13, off, 64);
    }
    // reuse the K-loop LDS for the reductions
    float* sred = (float*)lds;            // 128 floats
    float* wl = (float*)(lds + 512);      // 64 floats
    float4* pbuf = (float4*)(lds + 1024); // 512 float4
    __syncthreads();  // all K-loop LDS traffic done
    if (frow == 0) {
        const int base = wn * 64 + wm * 32 + fq * 4;
        sred[base + 0] = p00; sred[base + 1] = p01;
        sred[base + 2] = p02; sred[base + 3] = p03;
        sred[base + 16 + 0] = p10; sred[base + 16 + 1] = p11;
        sred[base + 16 + 2] = p12; sred[base + 16 + 3] = p13;
    }
    __syncthreads();
    // --- local softmax over this block's 64 rows (wave 0 only) ---
    if (t < 64) {
        const int s = s0 + t;
        float sc = sred[t] + sred[64 + t] + b2[0];
        const bool msk = (mask[b * S_ + s] == 0);
        if (msk) sc = MASKED_SCORE;
        scores[b * S_ + s] = sc;
        float mloc = sc;
        #pragma unroll
        for (int off = 1; off < 64; off <<= 1)
            mloc = fmaxf(mloc, __shfl_xor(mloc, off, 64));
        const float ws = msk ? 0.f : __expf(sc - mloc);
        float lloc = ws;
        #pragma unroll
        for (int off = 1; off < 64; off <<= 1)
            lloc += __shfl_xor(lloc, off, 64);
        if (t == 0) {
            mstat[b * NCH + ch] = mloc;
            lstat[b * NCH + ch] = lloc;
        }
        wl[t] = ws;
    }
    __syncthreads();
    // --- partial summary: Σ_s w_s · ctx[s,:]  (ctx rows are L2-hot) ---
    const int col = t & 63;  // float4 col idx (cols col and col+64)
    const int q = t >> 6;    // s ≡ q (mod 4)
    float4 alo = make_float4(0.f, 0.f, 0.f, 0.f);
    float4 ahi = make_float4(0.f, 0.f, 0.f, 0.f);
    #pragma unroll 4
    for (int s = q; s < RT; s += 4) {
        const float al = wl[s];
        const float4* row = (const float4*)(ctxb + (size_t)s * CTXD_);
        float4 v0 = row[col];
        float4 v1 = row[col + 64];
        alo.x += v0.x * al; alo.y += v0.y * al;
        alo.z += v0.z * al; alo.w += v0.w * al;
        ahi.x += v1.x * al; ahi.y += v1.y * al;
        ahi.z += v1.z * al; ahi.w += v1.w * al;
    }
    pbuf[q * 128 + col] = alo;
    pbuf[q * 128 + col + 64] = ahi;
    __syncthreads();
    if (t < 128) {
        float4 a0 = pbuf[t], a1 = pbuf[128 + t], a2 = pbuf[256 + t], a3 = pbuf[384 + t];
        float4 r;
        r.x = a0.x + a1.x + a2.x + a3.x;
        r.y = a0.y + a1.y + a2.y + a3.y;
        r.z = a0.z + a1.z + a2.z + a3.z;
        r.w = a0.w + a1.w + a2.w + a3.w;
        ((float4*)(part + ((size_t)(b * NCH + ch)) * CTXD_))[t] = r;
    }
}

// ---------------------------------------------------------------------------
// Kernel 2: combine — grid (4, B). Each block redoes the cheap per-chunk
// stats reduce (NCH=64), then handles a 128-col slice of summary and a
// 1024-row slice of alphas.
// ---------------------------------------------------------------------------
__global__ __launch_bounds__(256) void combine_kernel(
    const float* __restrict__ mstat, const float* __restrict__ lstat,
    const float* __restrict__ part, const float* __restrict__ scores,
    float* __restrict__ alphas, float* __restrict__ summary) {
    const int b = blockIdx.y, seg = blockIdx.x, t = threadIdx.x;
    __shared__ float e[NCH];
    __shared__ float gstat[2];  // m, invl
    if (t < NCH) {
        const float mi = mstat[b * NCH + t];
        const float li = lstat[b * NCH + t];
        float m = mi;
        #pragma unroll
        for (int off = 1; off < 64; off <<= 1)
            m = fmaxf(m, __shfl_xor(m, off, 64));
        const float ei = __expf(mi - m);  // all-masked chunk: underflows to 0
        float l = ei * li;
        #pragma unroll
        for (int off = 1; off < 64; off <<= 1)
            l += __shfl_xor(l, off, 64);
        e[t] = ei;
        if (t == 0) { gstat[0] = m; gstat[1] = 1.0f / l; }
    }
    __syncthreads();
    const float m = gstat[0], il = gstat[1];
    // summary slice: cols [seg*128, seg*128+128) = 32 float4
    const int c4 = t & 31;   // float4 within slice
    const int grp = t >> 5;  // 0..7: chunk phase
    float4 acc = make_float4(0.f, 0.f, 0.f, 0.f);
    for (int chv = grp; chv < NCH; chv += 8) {
        const float ei = e[chv];
        float4 v =
            ((const float4*)(part + ((size_t)(b * NCH + chv)) * CTXD_ + seg * 128))[c4];
        acc.x += ei * v.x; acc.y += ei * v.y;
        acc.z += ei * v.z; acc.w += ei * v.w;
    }
    __shared__ float4 buf[8][32];
    buf[grp][c4] = acc;
    __syncthreads();
    if (t < 32) {
        float4 r = make_float4(0.f, 0.f, 0.f, 0.f);
        #pragma unroll
        for (int g = 0; g < 8; ++g) {
            float4 v = buf[g][t];
            r.x += v.x; r.y += v.y; r.z += v.z; r.w += v.w;
        }
        r.x *= il; r.y *= il; r.z *= il; r.w *= il;
        ((float4*)(summary + (size_t)b * CTXD_ + seg * 128))[t] = r;
    }
    // alphas slice: s in [seg*1024, +1024)
    const int sbase = seg * 1024;
    #pragma unroll
    for (int i = 0; i < 4; ++i) {
        const int s = sbase + i * 256 + t;
        alphas[b * S_ + s] = __expf(scores[b * S_ + s] - m) * il;
    }
}

extern "C" void kernel_launch(void* const* d_in, const int* in_sizes, int n_in,
                              void* d_out, int out_size, void* d_ws,
                              size_t ws_size, hipStream_t stream) {
    const float* qry = (const float*)d_in[0];
    const float* ctx = (const float*)d_in[1];
    const int* mask = (const int*)d_in[2];
    const float* W = (const float*)d_in[3];
    const float* bias = (const float*)d_in[4];
    const float* w2 = (const float*)d_in[5];
    const float* b2 = (const float*)d_in[6];

    float* out = (float*)d_out;
    float* alphas = out;                         // B*S
    float* summary = out + B_ * S_;              // B*CTXD
    float* scores = out + B_ * S_ + B_ * CTXD_;  // B*S

    // ws layout: [Wt_lin bf16 256KB][qh 32KB][mstat 8KB][lstat 8KB][part 4MB]
    unsigned short* Wt_lin = (unsigned short*)d_ws;
    float* qh = (float*)((char*)d_ws + (size_t)ATTD_ * CTXD_ * 2);
    float* mstat = qh + B_ * ATTD_;
    float* lstat = mstat + B_ * NCH;
    float* part = lstat + B_ * NCH;

    prep_kernel<<<64, 256, 0, stream>>>(W, qry, bias, Wt_lin, qh);
    scores_kernel<<<dim3(NCH, B_), 256, 0, stream>>>(ctx, Wt_lin, qh, w2, b2,
                                                     mask, scores, mstat, lstat,
                                                     part);
    combine_kernel<<<dim3(4, B_), 256, 0, stream>>>(mstat, lstat, part, scores,
                                                    alphas, summary);
}